// Round 9
// baseline (305.866 us; speedup 1.0000x reference)
//
#include <hip/hip_runtime.h>
#include <cstdint>
#include <cstddef>

#define DECAYF 0.99f
#define OMDF   0.01f
#define EPSF   1e-5f
#define MARGIN 0.075f  // fp16 score-error bound

constexpr int N_ROWS = 64 * 2048;   // 131072
constexpr int D      = 128;
constexpr int K      = 1024;
constexpr int RSLICE = 8;           // code slices in rescore (128 codes each)
constexpr int CHUNK  = 64;          // rowlist rows per segsum block
constexpr int MROWS  = 256;         // rows per mfma_dist block (r6 optimum)

#define GLOBAL_AS __attribute__((address_space(1)))
#define LDS_AS    __attribute__((address_space(3)))

typedef _Float16 f16x8 __attribute__((ext_vector_type(8)));  // 8 f16 = 4 VGPRs
typedef __attribute__((ext_vector_type(4))) float f32x4;

union U8 { f16x8 v; uint4 u; };

__device__ __forceinline__ unsigned short f2h(float f) {
    union { _Float16 h; unsigned short u; } cv;
    cv.h = (_Float16)f;   // RNE
    return cv.u;
}

__device__ __forceinline__ float med3f(float a, float b, float c) {
#if __has_builtin(__builtin_amdgcn_fmed3f)
    return __builtin_amdgcn_fmed3f(a, b, c);
#else
    return fmaxf(fminf(a, b), c);
#endif
}

// ---------------------------------------------------------------------------
// Fused: eh = f16(2*e) (exact x2), cnorm[k] = ||e_k||^2, cnp = f16 hi/lo(-cn)
// One thread per codebook row. 4 blocks x 256 threads.
// ---------------------------------------------------------------------------
__global__ __launch_bounds__(256) void prep_embed(const float* __restrict__ e,
                                                  unsigned short* __restrict__ eh,
                                                  float* __restrict__ cnorm,
                                                  unsigned* __restrict__ cnp) {
    int k = blockIdx.x * 256 + threadIdx.x;
    if (k >= K) return;
    const float4* e4 = (const float4*)(e + (size_t)k * D);
    uint4* oh = (uint4*)(eh + (size_t)k * D);
    float a0 = 0.f, a1 = 0.f, a2 = 0.f, a3 = 0.f;
#pragma unroll
    for (int i = 0; i < D / 8; ++i) {
        float4 p = e4[2 * i], q = e4[2 * i + 1];
        a0 += p.x * p.x + q.x * q.x;
        a1 += p.y * p.y + q.y * q.y;
        a2 += p.z * p.z + q.z * q.z;
        a3 += p.w * p.w + q.w * q.w;
        uint4 o;
        o.x = (unsigned)f2h(2.f * p.x) | ((unsigned)f2h(2.f * p.y) << 16);
        o.y = (unsigned)f2h(2.f * p.z) | ((unsigned)f2h(2.f * p.w) << 16);
        o.z = (unsigned)f2h(2.f * q.x) | ((unsigned)f2h(2.f * q.y) << 16);
        o.w = (unsigned)f2h(2.f * q.z) | ((unsigned)f2h(2.f * q.w) << 16);
        oh[i] = o;
    }
    float cn = (a0 + a1) + (a2 + a3);
    cnorm[k] = cn;
    unsigned short h = f2h(-cn);
    union { unsigned short u; _Float16 hf; } cvh; cvh.u = h;
    float hr = (float)cvh.hf;
    unsigned short l = f2h(-cn - hr);
    cnp[k] = (unsigned)h | ((unsigned)l << 16);
}

// ---------------------------------------------------------------------------
// MFMA distance (fp16) + approx argmax with best/best2 margin flagging.
//  - 256 rows/block, 4 waves; 512 blocks = 2/CU (r6 empirical optimum)
//  - B staged in LDS via global_load_lds: 128 codes = 32 KB/buffer, double-
//    buffered -> 8 barriers total (half of r6); one eh stream per BLOCK
//  - manual unroll-by-2 makes `buf` a literal; per-lane swizzled ds_read
//    offsets precomputed once -> ds_read_b128 with constant offset: imm
//  - XOR block-swizzle on global source + ds_read side (linear LDS dest)
//  - staging (64 KB) aliases merge arrays (51 KB, post-loop only)
//  - -||e||^2 folded into MFMA via hi/lo f16 bias row
// ---------------------------------------------------------------------------
__global__ __launch_bounds__(256) void mfma_dist(const float* __restrict__ x,
                                                 const unsigned short* __restrict__ eh,
                                                 const unsigned* __restrict__ cnp,
                                                 float* __restrict__ out_idx,
                                                 int* __restrict__ idx_i32,
                                                 int* __restrict__ flag_cnt,
                                                 int* __restrict__ flag_list) {
    __shared__ __align__(16) float smem[16384];   // 65536 B
    // staging: 2 x 32 KB at the front (K loop only); merge arrays alias it.
    unsigned short* bstage = (unsigned short*)smem;
    float* sb1 = smem;
    float* sb2 = smem + MROWS * 17;
    float* sid = smem + MROWS * 17 * 2;

    const int tid = threadIdx.x;
    const int wave = tid >> 6;
    const int lane = tid & 63;
    const int l15 = lane & 15;
    const int quad = lane >> 4;
    const int rowbase = blockIdx.x * MROWS + wave * 64;

    // preload A-frags: 4 sets x 4 d-chunks, convert fp32->fp16 inline
    f16x8 a[4][4];
    {
        const float4* x4 = (const float4*)x;
#pragma unroll
        for (int s = 0; s < 4; ++s) {
            int row = rowbase + s * 16 + l15;
#pragma unroll
            for (int c = 0; c < 4; ++c) {
                size_t b4 = ((size_t)row * D + c * 32 + quad * 8) >> 2;
                float4 p = x4[b4], q = x4[b4 + 1];
                f16x8 f;
                f[0] = (_Float16)p.x; f[1] = (_Float16)p.y;
                f[2] = (_Float16)p.z; f[3] = (_Float16)p.w;
                f[4] = (_Float16)q.x; f[5] = (_Float16)q.y;
                f[6] = (_Float16)q.z; f[7] = (_Float16)q.w;
                a[s][c] = f;
            }
        }
    }

    // constant A-frag for the bias row: k-slots 0,1 = 1.0 (quad 0 lanes only)
    U8 acn;
    acn.u.x = (quad == 0) ? 0x3C003C00u : 0u;
    acn.u.y = 0u; acn.u.z = 0u; acn.u.w = 0u;

    float b1[4][4], b2[4][4], idf[4][4];
#pragma unroll
    for (int s = 0; s < 4; ++s)
#pragma unroll
        for (int r = 0; r < 4; ++r) { b1[s][r] = -3.4e38f; b2[s][r] = -3.4e38f; idf[s][r] = 0.f; }

    // precomputed per-lane swizzled LDS read offsets (shorts), one per d-chunk
    int lofs[4];
#pragma unroll
    for (int c = 0; c < 4; ++c)
        lofs[c] = l15 * 128 + (((c * 4 + quad) ^ (l15 & 7)) * 8);

    // stage 128 codes (32 KB) into buffer `buf`; cp = 128-code group (0..7).
    // LDS dest linear (wave-uniform base + HW lane*16); global source
    // pre-applies the block swizzle gblk = bslot ^ (row&7).
    auto stage = [&](int buf, int cp) {
#pragma unroll
        for (int j = 0; j < 8; ++j) {
            int sec = wave * 8 + j;                  // 0..31, 1 KB sectors
            int row = sec * 4 + quad;                // 0..127 (code in group)
            int gblk = l15 ^ (row & 7);
            const char* g = (const char*)eh + (size_t)cp * 32768 + row * 256 + gblk * 16;
            char* l = (char*)bstage + buf * 32768 + sec * 1024;
            __builtin_amdgcn_global_load_lds((const GLOBAL_AS void*)g,
                                             (LDS_AS void*)l, 16, 0, 0);
        }
    };

    // read B fragment for 16-code chunk k (0..7) of buffer buf (both literal)
    auto load_b = [&](f16x8* dst, int buf, int k) {
#pragma unroll
        for (int c = 0; c < 4; ++c)
            dst[c] = *(const f16x8*)(bstage + buf * 16384 + k * 2048 + lofs[c]);
    };

    auto compute = [&](const f16x8* bfr, unsigned cnw, float colf) {
        U8 bcn;
        bcn.u.x = (quad == 0) ? cnw : 0u;
        bcn.u.y = 0u; bcn.u.z = 0u; bcn.u.w = 0u;
        f32x4 zero = {0.f, 0.f, 0.f, 0.f};
        f32x4 cnacc = __builtin_amdgcn_mfma_f32_16x16x32_f16(acn.v, bcn.v, zero, 0, 0, 0);
#pragma unroll
        for (int s = 0; s < 4; ++s) {
            f32x4 acc = cnacc;
#pragma unroll
            for (int c = 0; c < 4; ++c)
                acc = __builtin_amdgcn_mfma_f32_16x16x32_f16(a[s][c], bfr[c], acc, 0, 0, 0);
#pragma unroll
            for (int r = 0; r < 4; ++r) {
                float sc = acc[r];               // = 2*x.e - ||e||^2 directly
                float old = b1[s][r];
                b1[s][r] = fmaxf(old, sc);
                b2[s][r] = med3f(sc, old, b2[s][r]);   // == max(min(sc,old),b2)
                idf[s][r] = (sc > old) ? colf : idf[s][r];
            }
        }
    };

    // one 128-code group: 8 chunks of 16 codes, buf is a compile-time literal
    auto body = [&](int buf, int cp) {
        const int base = cp * 128;
        unsigned cw[8];
#pragma unroll
        for (int k = 0; k < 8; ++k) cw[k] = cnp[base + k * 16 + l15];
#pragma unroll
        for (int kk = 0; kk < 4; ++kk) {
            f16x8 bf0[4], bf1[4];
            load_b(bf0, buf, 2 * kk);
            load_b(bf1, buf, 2 * kk + 1);
            compute(bf0, cw[2 * kk], (float)(base + 32 * kk + l15));
            compute(bf1, cw[2 * kk + 1], (float)(base + 32 * kk + 16 + l15));
        }
    };

    constexpr int ITERS = K / 128;   // 8
    stage(0, 0);
    __syncthreads();                 // drains vmcnt(0) before barrier

    for (int t = 0; t < ITERS / 2; ++t) {          // 4 iterations, buf literal
        stage(1, 2 * t + 1);                       // prefetch odd group
        body(0, 2 * t);
        __syncthreads();
        if (t + 1 < ITERS / 2) stage(0, 2 * t + 2); // prefetch next even group
        body(1, 2 * t + 1);
        __syncthreads();
    }

    // K loop done; final barrier above separates staging reads from merge
    // writes (the arrays alias). dump per-lane candidates.
#pragma unroll
    for (int s = 0; s < 4; ++s)
#pragma unroll
        for (int r = 0; r < 4; ++r) {
            int lr = wave * 64 + s * 16 + quad * 4 + r;
            sb1[lr * 17 + l15] = b1[s][r];
            sb2[lr * 17 + l15] = b2[s][r];
            sid[lr * 17 + l15] = idf[s][r];
        }
    __syncthreads();

    // one thread per row: merge 16 (b1,b2,idx) candidates
    {
        float bs = sb1[tid * 17], ss = sb2[tid * 17], bi = sid[tid * 17];
#pragma unroll
        for (int j = 1; j < 16; ++j) {
            float v = sb1[tid * 17 + j];
            float w = sb2[tid * 17 + j];
            float id = sid[tid * 17 + j];
            if (v > bs) { ss = fmaxf(bs, w); bi = id; bs = v; }
            else {
                ss = fmaxf(ss, v);
                if (v == bs && id < bi) bi = id;
            }
        }
        int grow = blockIdx.x * MROWS + tid;
        out_idx[grow] = bi;
        idx_i32[grow] = (int)bi;
        if (bs - ss < MARGIN) {
            int p = atomicAdd(flag_cnt, 1);
            flag_list[p] = grow;
        }
    }
}

// ---------------------------------------------------------------------------
// Exact fp32 rescore of flagged rows, CODE-SLICED across blocks.
// grid = (chunks grid-stride, RSLICE). Each block: 128 rows x 128 codes.
// Partial per-row argmax merged via packed u64 atomicMax:
//   key = orderable(score) << 32 | (0xFFFF - idx)   (max score, min idx on tie)
// ---------------------------------------------------------------------------
__global__ __launch_bounds__(256, 1) void rescore_part(const float* __restrict__ x,
                                                       const float* __restrict__ embed,
                                                       const float* __restrict__ cnorm,
                                                       const int* __restrict__ flag_cnt,
                                                       const int* __restrict__ flag_list,
                                                       unsigned long long* __restrict__ rkey) {
    __shared__ float xs[128][132];
    __shared__ float es[128][132];

    const int tid = threadIdx.x;
    const int tx = tid & 15;
    const int ty = tid >> 4;
    const int sl = blockIdx.y;                 // code slice: [sl*128, sl*128+128)
    const int cnt = *flag_cnt;
    const int nch = (cnt + 127) >> 7;

    for (int ch = blockIdx.x; ch < nch; ch += gridDim.x) {
        __syncthreads();
        // stage 128 flagged x rows
        {
            const float4* x4 = (const float4*)x;
#pragma unroll
            for (int it = 0; it < 16; ++it) {
                int idx = it * 256 + tid;
                int slot = idx >> 5, c4 = idx & 31;
                int fi = ch * 128 + slot;
                int grow = flag_list[fi < cnt ? fi : cnt - 1];
                float4 v = x4[(size_t)grow * 32 + c4];
                *(float4*)&xs[slot][c4 * 4] = v;
            }
        }
        // stage this slice's 128 embed rows
        {
            const float4* e4 = (const float4*)embed;
            const size_t base4 = (size_t)sl * 128 * 32;
#pragma unroll
            for (int it = 0; it < 16; ++it) {
                int idx = it * 256 + tid;
                int row = idx >> 5, c4 = idx & 31;
                float4 v = e4[base4 + idx];
                *(float4*)&es[row][c4 * 4] = v;
            }
        }
        float cn[8];
#pragma unroll
        for (int c = 0; c < 8; ++c) cn[c] = cnorm[sl * 128 + tx + 16 * c];
        __syncthreads();

        float acc[8][8];
#pragma unroll
        for (int r = 0; r < 8; ++r)
#pragma unroll
            for (int c = 0; c < 8; ++c) acc[r][c] = 0.f;

#pragma unroll 2
        for (int d4 = 0; d4 < 32; ++d4) {
            float4 av[8], bv[8];
#pragma unroll
            for (int r = 0; r < 8; ++r) av[r] = *(const float4*)&xs[ty + 16 * r][4 * d4];
#pragma unroll
            for (int c = 0; c < 8; ++c) bv[c] = *(const float4*)&es[tx + 16 * c][4 * d4];
#pragma unroll
            for (int r = 0; r < 8; ++r)
#pragma unroll
                for (int c = 0; c < 8; ++c) {
                    acc[r][c] = fmaf(av[r].x, bv[c].x, acc[r][c]);
                    acc[r][c] = fmaf(av[r].y, bv[c].y, acc[r][c]);
                    acc[r][c] = fmaf(av[r].z, bv[c].z, acc[r][c]);
                    acc[r][c] = fmaf(av[r].w, bv[c].w, acc[r][c]);
                }
        }

        float best[8];
        int bidx[8];
#pragma unroll
        for (int r = 0; r < 8; ++r) { best[r] = -3.4e38f; bidx[r] = 0; }
#pragma unroll
        for (int r = 0; r < 8; ++r)
#pragma unroll
            for (int c = 0; c < 8; ++c) {
                float s = 2.0f * acc[r][c] - cn[c];
                // codes ascend with c, so strict > keeps the lowest tied index
                if (s > best[r]) { best[r] = s; bidx[r] = sl * 128 + tx + 16 * c; }
            }

        __syncthreads();
        float* sbest = &es[0][0];
        int*   sidx  = (int*)&xs[0][0];
#pragma unroll
        for (int r = 0; r < 8; ++r) {
            int row = ty + 16 * r;
            sbest[row * 16 + tx] = best[r];
            sidx[row * 16 + tx] = bidx[r];
        }
        __syncthreads();
        if (tid < 128) {
            float bs = sbest[tid * 16];
            int bi = sidx[tid * 16];
#pragma unroll
            for (int j = 1; j < 16; ++j) {
                float s = sbest[tid * 16 + j];
                int id = sidx[tid * 16 + j];
                if (s > bs || (s == bs && id < bi)) { bs = s; bi = id; }
            }
            int fi = ch * 128 + tid;
            if (fi < cnt) {
                unsigned ub = __float_as_uint(bs);
                ub = (ub & 0x80000000u) ? ~ub : (ub | 0x80000000u);
                unsigned long long key =
                    ((unsigned long long)ub << 32) | (unsigned)(0xFFFFu - bi);
                atomicMax(&rkey[fi], key);
            }
        }
    }
}

__global__ __launch_bounds__(256) void rescore_final(const int* __restrict__ flag_cnt,
                                                     const int* __restrict__ flag_list,
                                                     const unsigned long long* __restrict__ rkey,
                                                     float* __restrict__ out_idx,
                                                     int* __restrict__ idx_i32) {
    const int cnt = *flag_cnt;
    for (int i = blockIdx.x * 256 + threadIdx.x; i < cnt; i += gridDim.x * 256) {
        unsigned long long key = rkey[i];
        int bi = 0xFFFF - (int)(key & 0xFFFFFFFFull);
        int grow = flag_list[i];
        out_idx[grow] = (float)bi;
        idx_i32[grow] = bi;
    }
}

// ---------------------------------------------------------------------------
// Histogram of final indices (LDS-privatized)
// ---------------------------------------------------------------------------
__global__ __launch_bounds__(256) void hist_kernel(const int* __restrict__ idx_i32,
                                                   int* __restrict__ counts_i) {
    __shared__ int h[K];
    for (int i = threadIdx.x; i < K; i += 256) h[i] = 0;
    __syncthreads();
    for (int row = blockIdx.x * 256 + threadIdx.x; row < N_ROWS; row += gridDim.x * 256)
        atomicAdd(&h[idx_i32[row]], 1);
    __syncthreads();
    for (int i = threadIdx.x; i < K; i += 256)
        if (h[i]) atomicAdd(&counts_i[i], h[i]);
}

// ---------------------------------------------------------------------------
// scan counts -> offsets/cursor; ncs, total, smoothed (1 block, 1024 thr)
// ---------------------------------------------------------------------------
__global__ __launch_bounds__(1024) void scan_cluster_kernel(const int* __restrict__ counts_i,
                                                            const float* __restrict__ cluster_size,
                                                            int* __restrict__ offsets,
                                                            int* __restrict__ cursor,
                                                            float* __restrict__ out_ncs,
                                                            float* __restrict__ smoothed) {
    __shared__ int s[1024];
    __shared__ float red[16];
    __shared__ float total_s;
    int k = threadIdx.x;
    int c = counts_i[k];
    s[k] = c;
    __syncthreads();
    for (int off = 1; off < 1024; off <<= 1) {
        int v = (k >= off) ? s[k - off] : 0;
        __syncthreads();
        s[k] += v;
        __syncthreads();
    }
    int offx = s[k] - c;   // exclusive
    offsets[k] = offx;
    cursor[k] = offx;

    float ncs = cluster_size[k] * DECAYF + OMDF * (float)c;
    out_ncs[k] = ncs;

    float v = ncs;
#pragma unroll
    for (int off = 32; off >= 1; off >>= 1) v += __shfl_down(v, off, 64);
    if ((k & 63) == 0) red[k >> 6] = v;
    __syncthreads();
    if (k < 16) {
        float t = red[k];
#pragma unroll
        for (int off = 8; off >= 1; off >>= 1) t += __shfl_down(t, off, 16);
        if (k == 0) total_s = t;
    }
    __syncthreads();
    float total = total_s;
    smoothed[k] = (ncs + EPSF) / (total + (float)K * EPSF) * total;
}

// ---------------------------------------------------------------------------
// scatter row ids (and their code) into per-code segments
// ---------------------------------------------------------------------------
__global__ __launch_bounds__(256) void scatter_kernel(const int* __restrict__ idx_i32,
                                                      int* __restrict__ cursor,
                                                      int* __restrict__ rowlist,
                                                      int* __restrict__ codelist) {
    int row = blockIdx.x * 256 + threadIdx.x;
    int code = idx_i32[row];
    int pos = atomicAdd(&cursor[code], 1);
    rowlist[pos] = row;
    codelist[pos] = code;
}

// ---------------------------------------------------------------------------
// Flat segmented gather-sum: each block owns exactly CHUNK consecutive
// rowlist entries (perfect balance). Register run-accumulation; atomic
// flush only at run boundaries.
// ---------------------------------------------------------------------------
__global__ __launch_bounds__(128) void segsum_flat(const float* __restrict__ x,
                                                   const int* __restrict__ rowlist,
                                                   const int* __restrict__ codelist,
                                                   float* __restrict__ embed_sum) {
    const int d = threadIdx.x;
    const int lo = blockIdx.x * CHUNK;

    float acc = 0.f;
    int cur = codelist[lo];
    for (int i = lo; i < lo + CHUNK; i += 8) {
        int r[8], c[8];
        float v[8];
#pragma unroll
        for (int j = 0; j < 8; ++j) {
            r[j] = rowlist[i + j];
            c[j] = codelist[i + j];
        }
#pragma unroll
        for (int j = 0; j < 8; ++j) v[j] = x[(size_t)r[j] * D + d];
#pragma unroll
        for (int j = 0; j < 8; ++j) {
            if (c[j] != cur) {
                atomicAdd(&embed_sum[(size_t)cur * D + d], acc);
                acc = 0.f;
                cur = c[j];
            }
            acc += v[j];
        }
    }
    atomicAdd(&embed_sum[(size_t)cur * D + d], acc);
}

// ---------------------------------------------------------------------------
// new_embed_avg / new_embed
// ---------------------------------------------------------------------------
__global__ __launch_bounds__(256) void embed_update_kernel(const float* __restrict__ embed_avg,
                                                           const float* __restrict__ embed_sum,
                                                           const float* __restrict__ smoothed,
                                                           float* __restrict__ out_nea,
                                                           float* __restrict__ out_ne) {
    int t = blockIdx.x * 256 + threadIdx.x;
    float4 ea = ((const float4*)embed_avg)[t];
    float4 es = ((const float4*)embed_sum)[t];
    float sm = smoothed[t >> 5];
    float4 nea;
    nea.x = ea.x * DECAYF + OMDF * es.x;
    nea.y = ea.y * DECAYF + OMDF * es.y;
    nea.z = ea.z * DECAYF + OMDF * es.z;
    nea.w = ea.w * DECAYF + OMDF * es.w;
    ((float4*)out_nea)[t] = nea;
    float4 ne;
    ne.x = nea.x / sm; ne.y = nea.y / sm; ne.z = nea.z / sm; ne.w = nea.w / sm;
    ((float4*)out_ne)[t] = ne;
}

// ---------------------------------------------------------------------------
// quantized[row] = embed[idx[row]]  (runs last: overwrites rkey/codelist scratch)
// ---------------------------------------------------------------------------
__global__ __launch_bounds__(256) void gather_kernel(const float* __restrict__ embed,
                                                     const int* __restrict__ idx_i32,
                                                     float* __restrict__ quant) {
    int t = blockIdx.x * 256 + threadIdx.x;
    int row = t >> 5;
    int j = t & 31;
    int k = idx_i32[row];
    ((float4*)quant)[(size_t)row * 32 + j] = ((const float4*)embed)[(size_t)k * 32 + j];
}

// ---------------------------------------------------------------------------
extern "C" void kernel_launch(void* const* d_in, const int* in_sizes, int n_in,
                              void* d_out, int out_size, void* d_ws, size_t ws_size,
                              hipStream_t stream) {
    const float* x            = (const float*)d_in[0];
    const float* embed        = (const float*)d_in[1];
    const float* embed_avg    = (const float*)d_in[2];
    const float* cluster_size = (const float*)d_in[3];

    float* out       = (float*)d_out;
    float* out_quant = out;
    float* out_idx   = out_quant + (size_t)N_ROWS * D;
    float* out_ne    = out_idx + N_ROWS;
    float* out_ncs   = out_ne + (size_t)K * D;
    float* out_nea   = out_ncs + K;

    // scratch in the quantized output region (overwritten by gather_kernel last):
    //   rkey: u64 argmax keys for flagged rows (1 MB)
    //   codelist: per-rowlist-slot code ids (0.5 MB)
    unsigned long long* rkey = (unsigned long long*)out_quant;
    int* codelist = (int*)(rkey + N_ROWS);

    // workspace (~2.4 MB)
    int*   counts_i  = (int*)d_ws;                        // K
    int*   flag_cnt  = counts_i + K;                      // 1 (+3 pad)
    int*   idx_i32   = counts_i + K + 4;                  // N
    int*   flag_list = idx_i32 + N_ROWS;                  // N
    int*   offsets   = flag_list + N_ROWS;                // K
    int*   cursor    = offsets + K;                       // K
    int*   rowlist   = cursor + K;                        // N
    float* cnorm     = (float*)(rowlist + N_ROWS);        // K
    float* smoothed  = cnorm + K;                         // K
    unsigned* cnp    = (unsigned*)(smoothed + K);         // K
    float* embed_sum = (float*)(cnp + K);                 // K*D
    unsigned short* eh = (unsigned short*)(embed_sum + (size_t)K * D);  // K*D f16

    hipMemsetAsync(counts_i, 0, (K + 4) * sizeof(int), stream);
    hipMemsetAsync(embed_sum, 0, (size_t)K * D * sizeof(float), stream);
    hipMemsetAsync(rkey, 0, (size_t)N_ROWS * sizeof(unsigned long long), stream);

    prep_embed<<<(K + 255) / 256, 256, 0, stream>>>(embed, eh, cnorm, cnp);
    mfma_dist<<<N_ROWS / MROWS, 256, 0, stream>>>(x, eh, cnp, out_idx, idx_i32,
                                                  flag_cnt, flag_list);
    rescore_part<<<dim3(128, RSLICE), 256, 0, stream>>>(x, embed, cnorm, flag_cnt,
                                                        flag_list, rkey);
    rescore_final<<<64, 256, 0, stream>>>(flag_cnt, flag_list, rkey, out_idx, idx_i32);
    hist_kernel<<<64, 256, 0, stream>>>(idx_i32, counts_i);
    scan_cluster_kernel<<<1, 1024, 0, stream>>>(counts_i, cluster_size, offsets, cursor,
                                                out_ncs, smoothed);
    scatter_kernel<<<N_ROWS / 256, 256, 0, stream>>>(idx_i32, cursor, rowlist, codelist);
    segsum_flat<<<N_ROWS / CHUNK, 128, 0, stream>>>(x, rowlist, codelist, embed_sum);
    embed_update_kernel<<<(K * D / 4) / 256, 256, 0, stream>>>(embed_avg, embed_sum, smoothed,
                                                               out_nea, out_ne);
    gather_kernel<<<(N_ROWS * 32) / 256, 256, 0, stream>>>(embed, idx_i32, out_quant);
}

// Round 10
// 289.439 us; speedup vs baseline: 1.0568x; 1.0568x over previous
//
#include <hip/hip_runtime.h>
#include <cstdint>
#include <cstddef>

#define DECAYF 0.99f
#define OMDF   0.01f
#define EPSF   1e-5f
#define MARGIN 0.075f  // fp16 score-error bound

constexpr int N_ROWS = 64 * 2048;   // 131072
constexpr int D      = 128;
constexpr int K      = 1024;
constexpr int RSLICE = 8;           // code slices in rescore (128 codes each)
constexpr int CHUNK  = 64;          // rowlist rows per segsum block
constexpr int MROWS  = 256;         // rows per mfma_dist block (r6 measured optimum)

#define GLOBAL_AS __attribute__((address_space(1)))
#define LDS_AS    __attribute__((address_space(3)))

typedef _Float16 f16x8 __attribute__((ext_vector_type(8)));  // 8 f16 = 4 VGPRs
typedef __attribute__((ext_vector_type(4))) float f32x4;

union U8 { f16x8 v; uint4 u; };

__device__ __forceinline__ unsigned short f2h(float f) {
    union { _Float16 h; unsigned short u; } cv;
    cv.h = (_Float16)f;   // RNE
    return cv.u;
}

// ---------------------------------------------------------------------------
// Fused prep: eh = f16(2*e), cnorm, cnp hi/lo(-cn); plus grid-stride zero
// fills of counts_i[K+4], embed_sum[K*D], rkey[N] (replaces 3 memset nodes).
// Grid: 64 blocks x 256.
// ---------------------------------------------------------------------------
__global__ __launch_bounds__(256) void prep_embed(const float* __restrict__ e,
                                                  unsigned short* __restrict__ eh,
                                                  float* __restrict__ cnorm,
                                                  unsigned* __restrict__ cnp,
                                                  int* __restrict__ counts_i,
                                                  float* __restrict__ embed_sum,
                                                  unsigned long long* __restrict__ rkey) {
    const int gid = blockIdx.x * 256 + threadIdx.x;   // 0..16383
    const uint4 z = {0u, 0u, 0u, 0u};
    {   // counts_i + flag_cnt pad: (K+4) ints = 257 uint4
        uint4* c4 = (uint4*)counts_i;
        for (int i = gid; i < 257; i += 64 * 256) c4[i] = z;
    }
    {   // embed_sum: K*D floats = 32768 uint4
        uint4* s4 = (uint4*)embed_sum;
        for (int i = gid; i < 32768; i += 64 * 256) s4[i] = z;
    }
    {   // rkey: N u64 = 65536 uint4
        uint4* r4 = (uint4*)rkey;
        for (int i = gid; i < 65536; i += 64 * 256) r4[i] = z;
    }

    const int k = gid;
    if (k >= K) return;
    const float4* e4 = (const float4*)(e + (size_t)k * D);
    uint4* oh = (uint4*)(eh + (size_t)k * D);
    float a0 = 0.f, a1 = 0.f, a2 = 0.f, a3 = 0.f;
#pragma unroll
    for (int i = 0; i < D / 8; ++i) {
        float4 p = e4[2 * i], q = e4[2 * i + 1];
        a0 += p.x * p.x + q.x * q.x;
        a1 += p.y * p.y + q.y * q.y;
        a2 += p.z * p.z + q.z * q.z;
        a3 += p.w * p.w + q.w * q.w;
        uint4 o;
        o.x = (unsigned)f2h(2.f * p.x) | ((unsigned)f2h(2.f * p.y) << 16);
        o.y = (unsigned)f2h(2.f * p.z) | ((unsigned)f2h(2.f * p.w) << 16);
        o.z = (unsigned)f2h(2.f * q.x) | ((unsigned)f2h(2.f * q.y) << 16);
        o.w = (unsigned)f2h(2.f * q.z) | ((unsigned)f2h(2.f * q.w) << 16);
        oh[i] = o;
    }
    float cn = (a0 + a1) + (a2 + a3);
    cnorm[k] = cn;
    unsigned short h = f2h(-cn);
    union { unsigned short u; _Float16 hf; } cvh; cvh.u = h;
    float hr = (float)cvh.hf;
    unsigned short l = f2h(-cn - hr);
    cnp[k] = (unsigned)h | ((unsigned)l << 16);
}

// ---------------------------------------------------------------------------
// MFMA distance (fp16) + approx argmax — r6 version verbatim (measured 67 us,
// 128 VGPR). 256 rows/block, 4 waves, 64-code LDS double-buffer via
// global_load_lds, XOR block-swizzle on source+read, staging aliases merge
// arrays (52 KB), -||e||^2 folded into MFMA via hi/lo f16 bias row.
// ---------------------------------------------------------------------------
__global__ __launch_bounds__(256) void mfma_dist(const float* __restrict__ x,
                                                 const unsigned short* __restrict__ eh,
                                                 const unsigned* __restrict__ cnp,
                                                 float* __restrict__ out_idx,
                                                 int* __restrict__ idx_i32,
                                                 int* __restrict__ flag_cnt,
                                                 int* __restrict__ flag_list) {
    __shared__ __align__(16) float smem[MROWS * 17 * 3];   // 52224 B
    unsigned short* bstage = (unsigned short*)smem;
    float* sb1 = smem;
    float* sb2 = smem + MROWS * 17;
    float* sid = smem + MROWS * 17 * 2;

    const int tid = threadIdx.x;
    const int wave = tid >> 6;
    const int lane = tid & 63;
    const int l15 = lane & 15;
    const int quad = lane >> 4;
    const int rowbase = blockIdx.x * MROWS + wave * 64;

    // preload A-frags: 4 sets x 4 d-chunks, convert fp32->fp16 inline
    f16x8 a[4][4];
    {
        const float4* x4 = (const float4*)x;
#pragma unroll
        for (int s = 0; s < 4; ++s) {
            int row = rowbase + s * 16 + l15;
#pragma unroll
            for (int c = 0; c < 4; ++c) {
                size_t b4 = ((size_t)row * D + c * 32 + quad * 8) >> 2;
                float4 p = x4[b4], q = x4[b4 + 1];
                f16x8 f;
                f[0] = (_Float16)p.x; f[1] = (_Float16)p.y;
                f[2] = (_Float16)p.z; f[3] = (_Float16)p.w;
                f[4] = (_Float16)q.x; f[5] = (_Float16)q.y;
                f[6] = (_Float16)q.z; f[7] = (_Float16)q.w;
                a[s][c] = f;
            }
        }
    }

    // constant A-frag for the bias row: k-slots 0,1 = 1.0 (quad 0 lanes only)
    U8 acn;
    acn.u.x = (quad == 0) ? 0x3C003C00u : 0u;
    acn.u.y = 0u; acn.u.z = 0u; acn.u.w = 0u;

    float b1[4][4], b2[4][4], idf[4][4];
#pragma unroll
    for (int s = 0; s < 4; ++s)
#pragma unroll
        for (int r = 0; r < 4; ++r) { b1[s][r] = -3.4e38f; b2[s][r] = -3.4e38f; idf[s][r] = 0.f; }

    auto stage = [&](int buf, int cp) {
#pragma unroll
        for (int j = 0; j < 4; ++j) {
            int sec = wave * 4 + j;                  // 0..15, 1 KB sectors
            int row = sec * 4 + (lane >> 4);         // 0..63 (code within group)
            int gblk = (lane & 15) ^ (row & 7);
            const char* g = (const char*)eh + (size_t)cp * 16384 + row * 256 + gblk * 16;
            char* l = (char*)bstage + buf * 16384 + sec * 1024;
            __builtin_amdgcn_global_load_lds((const GLOBAL_AS void*)g,
                                             (LDS_AS void*)l, 16, 0, 0);
        }
    };

    auto load_b = [&](f16x8* dst, unsigned& cnw, int buf, int k, int cb) {
        const unsigned short* bb = bstage + buf * 8192 + k * 2048 + l15 * 128;
#pragma unroll
        for (int c = 0; c < 4; ++c) {
            int blk = (c * 4 + quad) ^ (l15 & 7);
            dst[c] = *(const f16x8*)(bb + blk * 8);
        }
        cnw = cnp[cb + l15];
    };

    auto compute = [&](const f16x8* bfr, unsigned cnw, float colf) {
        U8 bcn;
        bcn.u.x = (quad == 0) ? cnw : 0u;
        bcn.u.y = 0u; bcn.u.z = 0u; bcn.u.w = 0u;
        f32x4 zero = {0.f, 0.f, 0.f, 0.f};
        f32x4 cnacc = __builtin_amdgcn_mfma_f32_16x16x32_f16(acn.v, bcn.v, zero, 0, 0, 0);
#pragma unroll
        for (int s = 0; s < 4; ++s) {
            f32x4 acc = cnacc;
#pragma unroll
            for (int c = 0; c < 4; ++c)
                acc = __builtin_amdgcn_mfma_f32_16x16x32_f16(a[s][c], bfr[c], acc, 0, 0, 0);
#pragma unroll
            for (int r = 0; r < 4; ++r) {
                float sc = acc[r];               // = 2*x.e - ||e||^2 directly
                float old = b1[s][r];
                b1[s][r] = fmaxf(old, sc);
                b2[s][r] = fmaxf(fminf(sc, old), b2[s][r]);
                idf[s][r] = (sc > old) ? colf : idf[s][r];
            }
        }
    };

    constexpr int ITERS = K / 64;   // 16
    stage(0, 0);
    __syncthreads();                // drains vmcnt(0) before barrier

    for (int cp = 0; cp < ITERS; ++cp) {
        if (cp + 1 < ITERS) stage((cp + 1) & 1, cp + 1);
        const int buf = cp & 1;
        const int base = cp * 64;
        f16x8 bf0[4], bf1[4];
        unsigned cw0, cw1;
        load_b(bf0, cw0, buf, 0, base);
        load_b(bf1, cw1, buf, 1, base + 16);
        compute(bf0, cw0, (float)(base + l15));
        compute(bf1, cw1, (float)(base + 16 + l15));
        load_b(bf0, cw0, buf, 2, base + 32);
        load_b(bf1, cw1, buf, 3, base + 48);
        compute(bf0, cw0, (float)(base + 32 + l15));
        compute(bf1, cw1, (float)(base + 48 + l15));
        __syncthreads();            // next-buffer staging landed; this buffer free
    }

    // dump per-lane candidates: row lr has 16 candidates (one per l15)
#pragma unroll
    for (int s = 0; s < 4; ++s)
#pragma unroll
        for (int r = 0; r < 4; ++r) {
            int lr = wave * 64 + s * 16 + quad * 4 + r;
            sb1[lr * 17 + l15] = b1[s][r];
            sb2[lr * 17 + l15] = b2[s][r];
            sid[lr * 17 + l15] = idf[s][r];
        }
    __syncthreads();

    // one thread per row: merge 16 (b1,b2,idx) candidates
    {
        float bs = sb1[tid * 17], ss = sb2[tid * 17], bi = sid[tid * 17];
#pragma unroll
        for (int j = 1; j < 16; ++j) {
            float v = sb1[tid * 17 + j];
            float w = sb2[tid * 17 + j];
            float id = sid[tid * 17 + j];
            if (v > bs) { ss = fmaxf(bs, w); bi = id; bs = v; }
            else {
                ss = fmaxf(ss, v);
                if (v == bs && id < bi) bi = id;
            }
        }
        int grow = blockIdx.x * MROWS + tid;
        out_idx[grow] = bi;
        idx_i32[grow] = (int)bi;
        if (bs - ss < MARGIN) {
            int p = atomicAdd(flag_cnt, 1);
            flag_list[p] = grow;
        }
    }
}

// ---------------------------------------------------------------------------
// Exact fp32 rescore of flagged rows, CODE-SLICED across blocks.
// grid = (chunks grid-stride, RSLICE). Each block: 128 rows x 128 codes.
// Partial per-row argmax merged via packed u64 atomicMax:
//   key = orderable(score) << 32 | (0xFFFF - idx)   (max score, min idx on tie)
// ---------------------------------------------------------------------------
__global__ __launch_bounds__(256, 1) void rescore_part(const float* __restrict__ x,
                                                       const float* __restrict__ embed,
                                                       const float* __restrict__ cnorm,
                                                       const int* __restrict__ flag_cnt,
                                                       const int* __restrict__ flag_list,
                                                       unsigned long long* __restrict__ rkey) {
    __shared__ float xs[128][132];
    __shared__ float es[128][132];

    const int tid = threadIdx.x;
    const int tx = tid & 15;
    const int ty = tid >> 4;
    const int sl = blockIdx.y;                 // code slice: [sl*128, sl*128+128)
    const int cnt = *flag_cnt;
    const int nch = (cnt + 127) >> 7;

    for (int ch = blockIdx.x; ch < nch; ch += gridDim.x) {
        __syncthreads();
        // stage 128 flagged x rows
        {
            const float4* x4 = (const float4*)x;
#pragma unroll
            for (int it = 0; it < 16; ++it) {
                int idx = it * 256 + tid;
                int slot = idx >> 5, c4 = idx & 31;
                int fi = ch * 128 + slot;
                int grow = flag_list[fi < cnt ? fi : cnt - 1];
                float4 v = x4[(size_t)grow * 32 + c4];
                *(float4*)&xs[slot][c4 * 4] = v;
            }
        }
        // stage this slice's 128 embed rows
        {
            const float4* e4 = (const float4*)embed;
            const size_t base4 = (size_t)sl * 128 * 32;
#pragma unroll
            for (int it = 0; it < 16; ++it) {
                int idx = it * 256 + tid;
                int row = idx >> 5, c4 = idx & 31;
                float4 v = e4[base4 + idx];
                *(float4*)&es[row][c4 * 4] = v;
            }
        }
        float cn[8];
#pragma unroll
        for (int c = 0; c < 8; ++c) cn[c] = cnorm[sl * 128 + tx + 16 * c];
        __syncthreads();

        float acc[8][8];
#pragma unroll
        for (int r = 0; r < 8; ++r)
#pragma unroll
            for (int c = 0; c < 8; ++c) acc[r][c] = 0.f;

#pragma unroll 2
        for (int d4 = 0; d4 < 32; ++d4) {
            float4 av[8], bv[8];
#pragma unroll
            for (int r = 0; r < 8; ++r) av[r] = *(const float4*)&xs[ty + 16 * r][4 * d4];
#pragma unroll
            for (int c = 0; c < 8; ++c) bv[c] = *(const float4*)&es[tx + 16 * c][4 * d4];
#pragma unroll
            for (int r = 0; r < 8; ++r)
#pragma unroll
                for (int c = 0; c < 8; ++c) {
                    acc[r][c] = fmaf(av[r].x, bv[c].x, acc[r][c]);
                    acc[r][c] = fmaf(av[r].y, bv[c].y, acc[r][c]);
                    acc[r][c] = fmaf(av[r].z, bv[c].z, acc[r][c]);
                    acc[r][c] = fmaf(av[r].w, bv[c].w, acc[r][c]);
                }
        }

        float best[8];
        int bidx[8];
#pragma unroll
        for (int r = 0; r < 8; ++r) { best[r] = -3.4e38f; bidx[r] = 0; }
#pragma unroll
        for (int r = 0; r < 8; ++r)
#pragma unroll
            for (int c = 0; c < 8; ++c) {
                float s = 2.0f * acc[r][c] - cn[c];
                // codes ascend with c, so strict > keeps the lowest tied index
                if (s > best[r]) { best[r] = s; bidx[r] = sl * 128 + tx + 16 * c; }
            }

        __syncthreads();
        float* sbest = &es[0][0];
        int*   sidx  = (int*)&xs[0][0];
#pragma unroll
        for (int r = 0; r < 8; ++r) {
            int row = ty + 16 * r;
            sbest[row * 16 + tx] = best[r];
            sidx[row * 16 + tx] = bidx[r];
        }
        __syncthreads();
        if (tid < 128) {
            float bs = sbest[tid * 16];
            int bi = sidx[tid * 16];
#pragma unroll
            for (int j = 1; j < 16; ++j) {
                float s = sbest[tid * 16 + j];
                int id = sidx[tid * 16 + j];
                if (s > bs || (s == bs && id < bi)) { bs = s; bi = id; }
            }
            int fi = ch * 128 + tid;
            if (fi < cnt) {
                unsigned ub = __float_as_uint(bs);
                ub = (ub & 0x80000000u) ? ~ub : (ub | 0x80000000u);
                unsigned long long key =
                    ((unsigned long long)ub << 32) | (unsigned)(0xFFFFu - bi);
                atomicMax(&rkey[fi], key);
            }
        }
    }
}

__global__ __launch_bounds__(256) void rescore_final(const int* __restrict__ flag_cnt,
                                                     const int* __restrict__ flag_list,
                                                     const unsigned long long* __restrict__ rkey,
                                                     float* __restrict__ out_idx,
                                                     int* __restrict__ idx_i32) {
    const int cnt = *flag_cnt;
    for (int i = blockIdx.x * 256 + threadIdx.x; i < cnt; i += gridDim.x * 256) {
        unsigned long long key = rkey[i];
        int bi = 0xFFFF - (int)(key & 0xFFFFFFFFull);
        int grow = flag_list[i];
        out_idx[grow] = (float)bi;
        idx_i32[grow] = bi;
    }
}

// ---------------------------------------------------------------------------
// Histogram of final indices (LDS-privatized)
// ---------------------------------------------------------------------------
__global__ __launch_bounds__(256) void hist_kernel(const int* __restrict__ idx_i32,
                                                   int* __restrict__ counts_i) {
    __shared__ int h[K];
    for (int i = threadIdx.x; i < K; i += 256) h[i] = 0;
    __syncthreads();
    for (int row = blockIdx.x * 256 + threadIdx.x; row < N_ROWS; row += gridDim.x * 256)
        atomicAdd(&h[idx_i32[row]], 1);
    __syncthreads();
    for (int i = threadIdx.x; i < K; i += 256)
        if (h[i]) atomicAdd(&counts_i[i], h[i]);
}

// ---------------------------------------------------------------------------
// scan counts -> offsets/cursor; ncs, total, smoothed (1 block, 1024 thr)
// ---------------------------------------------------------------------------
__global__ __launch_bounds__(1024) void scan_cluster_kernel(const int* __restrict__ counts_i,
                                                            const float* __restrict__ cluster_size,
                                                            int* __restrict__ offsets,
                                                            int* __restrict__ cursor,
                                                            float* __restrict__ out_ncs,
                                                            float* __restrict__ smoothed) {
    __shared__ int s[1024];
    __shared__ float red[16];
    __shared__ float total_s;
    int k = threadIdx.x;
    int c = counts_i[k];
    s[k] = c;
    __syncthreads();
    for (int off = 1; off < 1024; off <<= 1) {
        int v = (k >= off) ? s[k - off] : 0;
        __syncthreads();
        s[k] += v;
        __syncthreads();
    }
    int offx = s[k] - c;   // exclusive
    offsets[k] = offx;
    cursor[k] = offx;

    float ncs = cluster_size[k] * DECAYF + OMDF * (float)c;
    out_ncs[k] = ncs;

    float v = ncs;
#pragma unroll
    for (int off = 32; off >= 1; off >>= 1) v += __shfl_down(v, off, 64);
    if ((k & 63) == 0) red[k >> 6] = v;
    __syncthreads();
    if (k < 16) {
        float t = red[k];
#pragma unroll
        for (int off = 8; off >= 1; off >>= 1) t += __shfl_down(t, off, 16);
        if (k == 0) total_s = t;
    }
    __syncthreads();
    float total = total_s;
    smoothed[k] = (ncs + EPSF) / (total + (float)K * EPSF) * total;
}

// ---------------------------------------------------------------------------
// scatter row ids (and their code) into per-code segments
// ---------------------------------------------------------------------------
__global__ __launch_bounds__(256) void scatter_kernel(const int* __restrict__ idx_i32,
                                                      int* __restrict__ cursor,
                                                      int* __restrict__ rowlist,
                                                      int* __restrict__ codelist) {
    int row = blockIdx.x * 256 + threadIdx.x;
    int code = idx_i32[row];
    int pos = atomicAdd(&cursor[code], 1);
    rowlist[pos] = row;
    codelist[pos] = code;
}

// ---------------------------------------------------------------------------
// Flat segmented gather-sum: each block owns exactly CHUNK consecutive
// rowlist entries (perfect balance). Register run-accumulation; atomic
// flush only at run boundaries.
// ---------------------------------------------------------------------------
__global__ __launch_bounds__(128) void segsum_flat(const float* __restrict__ x,
                                                   const int* __restrict__ rowlist,
                                                   const int* __restrict__ codelist,
                                                   float* __restrict__ embed_sum) {
    const int d = threadIdx.x;
    const int lo = blockIdx.x * CHUNK;

    float acc = 0.f;
    int cur = codelist[lo];
    for (int i = lo; i < lo + CHUNK; i += 8) {
        int r[8], c[8];
        float v[8];
#pragma unroll
        for (int j = 0; j < 8; ++j) {
            r[j] = rowlist[i + j];
            c[j] = codelist[i + j];
        }
#pragma unroll
        for (int j = 0; j < 8; ++j) v[j] = x[(size_t)r[j] * D + d];
#pragma unroll
        for (int j = 0; j < 8; ++j) {
            if (c[j] != cur) {
                atomicAdd(&embed_sum[(size_t)cur * D + d], acc);
                acc = 0.f;
                cur = c[j];
            }
            acc += v[j];
        }
    }
    atomicAdd(&embed_sum[(size_t)cur * D + d], acc);
}

// ---------------------------------------------------------------------------
// new_embed_avg / new_embed
// ---------------------------------------------------------------------------
__global__ __launch_bounds__(256) void embed_update_kernel(const float* __restrict__ embed_avg,
                                                           const float* __restrict__ embed_sum,
                                                           const float* __restrict__ smoothed,
                                                           float* __restrict__ out_nea,
                                                           float* __restrict__ out_ne) {
    int t = blockIdx.x * 256 + threadIdx.x;
    float4 ea = ((const float4*)embed_avg)[t];
    float4 es = ((const float4*)embed_sum)[t];
    float sm = smoothed[t >> 5];
    float4 nea;
    nea.x = ea.x * DECAYF + OMDF * es.x;
    nea.y = ea.y * DECAYF + OMDF * es.y;
    nea.z = ea.z * DECAYF + OMDF * es.z;
    nea.w = ea.w * DECAYF + OMDF * es.w;
    ((float4*)out_nea)[t] = nea;
    float4 ne;
    ne.x = nea.x / sm; ne.y = nea.y / sm; ne.z = nea.z / sm; ne.w = nea.w / sm;
    ((float4*)out_ne)[t] = ne;
}

// ---------------------------------------------------------------------------
// quantized[row] = embed[idx[row]]  (runs last: overwrites rkey/codelist scratch)
// ---------------------------------------------------------------------------
__global__ __launch_bounds__(256) void gather_kernel(const float* __restrict__ embed,
                                                     const int* __restrict__ idx_i32,
                                                     float* __restrict__ quant) {
    int t = blockIdx.x * 256 + threadIdx.x;
    int row = t >> 5;
    int j = t & 31;
    int k = idx_i32[row];
    ((float4*)quant)[(size_t)row * 32 + j] = ((const float4*)embed)[(size_t)k * 32 + j];
}

// ---------------------------------------------------------------------------
extern "C" void kernel_launch(void* const* d_in, const int* in_sizes, int n_in,
                              void* d_out, int out_size, void* d_ws, size_t ws_size,
                              hipStream_t stream) {
    const float* x            = (const float*)d_in[0];
    const float* embed        = (const float*)d_in[1];
    const float* embed_avg    = (const float*)d_in[2];
    const float* cluster_size = (const float*)d_in[3];

    float* out       = (float*)d_out;
    float* out_quant = out;
    float* out_idx   = out_quant + (size_t)N_ROWS * D;
    float* out_ne    = out_idx + N_ROWS;
    float* out_ncs   = out_ne + (size_t)K * D;
    float* out_nea   = out_ncs + K;

    // scratch in the quantized output region (overwritten by gather_kernel last):
    //   rkey: u64 argmax keys for flagged rows (1 MB)
    //   codelist: per-rowlist-slot code ids (0.5 MB)
    unsigned long long* rkey = (unsigned long long*)out_quant;
    int* codelist = (int*)(rkey + N_ROWS);

    // workspace (~2.4 MB)
    int*   counts_i  = (int*)d_ws;                        // K (+4 pad incl flag_cnt)
    int*   flag_cnt  = counts_i + K;                      // 1 (+3 pad)
    int*   idx_i32   = counts_i + K + 4;                  // N
    int*   flag_list = idx_i32 + N_ROWS;                  // N
    int*   offsets   = flag_list + N_ROWS;                // K
    int*   cursor    = offsets + K;                       // K
    int*   rowlist   = cursor + K;                        // N
    float* cnorm     = (float*)(rowlist + N_ROWS);        // K
    float* smoothed  = cnorm + K;                         // K
    unsigned* cnp    = (unsigned*)(smoothed + K);         // K
    float* embed_sum = (float*)(cnp + K);                 // K*D
    unsigned short* eh = (unsigned short*)(embed_sum + (size_t)K * D);  // K*D f16

    // prep_embed also zero-fills counts_i[K+4], embed_sum, rkey (3 memsets folded)
    prep_embed<<<64, 256, 0, stream>>>(embed, eh, cnorm, cnp, counts_i, embed_sum, rkey);
    mfma_dist<<<N_ROWS / MROWS, 256, 0, stream>>>(x, eh, cnp, out_idx, idx_i32,
                                                  flag_cnt, flag_list);
    rescore_part<<<dim3(128, RSLICE), 256, 0, stream>>>(x, embed, cnorm, flag_cnt,
                                                        flag_list, rkey);
    rescore_final<<<64, 256, 0, stream>>>(flag_cnt, flag_list, rkey, out_idx, idx_i32);
    hist_kernel<<<64, 256, 0, stream>>>(idx_i32, counts_i);
    scan_cluster_kernel<<<1, 1024, 0, stream>>>(counts_i, cluster_size, offsets, cursor,
                                                out_ncs, smoothed);
    scatter_kernel<<<N_ROWS / 256, 256, 0, stream>>>(idx_i32, cursor, rowlist, codelist);
    segsum_flat<<<N_ROWS / CHUNK, 128, 0, stream>>>(x, rowlist, codelist, embed_sum);
    embed_update_kernel<<<(K * D / 4) / 256, 256, 0, stream>>>(embed_avg, embed_sum, smoothed,
                                                               out_nea, out_ne);
    gather_kernel<<<(N_ROWS * 32) / 256, 256, 0, stream>>>(embed, idx_i32, out_quant);
}

// Round 11
// 283.372 us; speedup vs baseline: 1.0794x; 1.0214x over previous
//
#include <hip/hip_runtime.h>
#include <cstdint>
#include <cstddef>

#define DECAYF 0.99f
#define OMDF   0.01f
#define EPSF   1e-5f
#define MARGIN 0.075f  // fp16 score-error bound

constexpr int N_ROWS = 64 * 2048;   // 131072
constexpr int D      = 128;
constexpr int K      = 1024;
constexpr int RSLICE = 8;           // code slices in rescore (128 codes each)
constexpr int CHUNK  = 64;          // rowlist rows per segsum block
constexpr int MROWS  = 256;         // rows per mfma_dist block (r6 measured optimum)

#define GLOBAL_AS __attribute__((address_space(1)))
#define LDS_AS    __attribute__((address_space(3)))

typedef _Float16 f16x8 __attribute__((ext_vector_type(8)));  // 8 f16 = 4 VGPRs
typedef __attribute__((ext_vector_type(4))) float f32x4;

union U8 { f16x8 v; uint4 u; };

__device__ __forceinline__ unsigned short f2h(float f) {
    union { _Float16 h; unsigned short u; } cv;
    cv.h = (_Float16)f;   // RNE
    return cv.u;
}

// ---------------------------------------------------------------------------
// Fused prep: eh = f16(2*e), cnorm, cnp hi/lo(-cn); plus grid-stride zero
// fills of counts_i[K+4], embed_sum[K*D], rkey[N] (replaces 3 memset nodes).
// Grid: 64 blocks x 256.
// ---------------------------------------------------------------------------
__global__ __launch_bounds__(256) void prep_embed(const float* __restrict__ e,
                                                  unsigned short* __restrict__ eh,
                                                  float* __restrict__ cnorm,
                                                  unsigned* __restrict__ cnp,
                                                  int* __restrict__ counts_i,
                                                  float* __restrict__ embed_sum,
                                                  unsigned long long* __restrict__ rkey) {
    const int gid = blockIdx.x * 256 + threadIdx.x;   // 0..16383
    const uint4 z = {0u, 0u, 0u, 0u};
    {   // counts_i + flag_cnt pad: (K+4) ints = 257 uint4
        uint4* c4 = (uint4*)counts_i;
        for (int i = gid; i < 257; i += 64 * 256) c4[i] = z;
    }
    {   // embed_sum: K*D floats = 32768 uint4
        uint4* s4 = (uint4*)embed_sum;
        for (int i = gid; i < 32768; i += 64 * 256) s4[i] = z;
    }
    {   // rkey: N u64 = 65536 uint4
        uint4* r4 = (uint4*)rkey;
        for (int i = gid; i < 65536; i += 64 * 256) r4[i] = z;
    }

    const int k = gid;
    if (k >= K) return;
    const float4* e4 = (const float4*)(e + (size_t)k * D);
    uint4* oh = (uint4*)(eh + (size_t)k * D);
    float a0 = 0.f, a1 = 0.f, a2 = 0.f, a3 = 0.f;
#pragma unroll
    for (int i = 0; i < D / 8; ++i) {
        float4 p = e4[2 * i], q = e4[2 * i + 1];
        a0 += p.x * p.x + q.x * q.x;
        a1 += p.y * p.y + q.y * q.y;
        a2 += p.z * p.z + q.z * q.z;
        a3 += p.w * p.w + q.w * q.w;
        uint4 o;
        o.x = (unsigned)f2h(2.f * p.x) | ((unsigned)f2h(2.f * p.y) << 16);
        o.y = (unsigned)f2h(2.f * p.z) | ((unsigned)f2h(2.f * p.w) << 16);
        o.z = (unsigned)f2h(2.f * q.x) | ((unsigned)f2h(2.f * q.y) << 16);
        o.w = (unsigned)f2h(2.f * q.z) | ((unsigned)f2h(2.f * q.w) << 16);
        oh[i] = o;
    }
    float cn = (a0 + a1) + (a2 + a3);
    cnorm[k] = cn;
    unsigned short h = f2h(-cn);
    union { unsigned short u; _Float16 hf; } cvh; cvh.u = h;
    float hr = (float)cvh.hf;
    unsigned short l = f2h(-cn - hr);
    cnp[k] = (unsigned)h | ((unsigned)l << 16);
}

// ---------------------------------------------------------------------------
// MFMA distance (fp16) + approx argmax + FOLDED per-block histogram.
// r6 structure (measured 67 us, 128 VGPR): 256 rows/block, 4 waves, 64-code
// LDS double-buffer via global_load_lds, XOR block-swizzle, staging aliases
// merge arrays, -||e||^2 folded into MFMA via hi/lo f16 bias row.
// New: LDS h[K] histogram of the block's 256 approx indices, flushed to
// counts_i (replaces hist_kernel; flagged-row deltas applied later in scan).
// ---------------------------------------------------------------------------
__global__ __launch_bounds__(256) void mfma_dist(const float* __restrict__ x,
                                                 const unsigned short* __restrict__ eh,
                                                 const unsigned* __restrict__ cnp,
                                                 float* __restrict__ out_idx,
                                                 int* __restrict__ idx_i32,
                                                 int* __restrict__ flag_cnt,
                                                 int* __restrict__ flag_list,
                                                 int* __restrict__ counts_i) {
    __shared__ __align__(16) float smem[MROWS * 17 * 3];   // 52224 B
    __shared__ int h[K];                                    // +4096 B = 56320 B
    unsigned short* bstage = (unsigned short*)smem;
    float* sb1 = smem;
    float* sb2 = smem + MROWS * 17;
    float* sid = smem + MROWS * 17 * 2;

    const int tid = threadIdx.x;
    const int wave = tid >> 6;
    const int lane = tid & 63;
    const int l15 = lane & 15;
    const int quad = lane >> 4;
    const int rowbase = blockIdx.x * MROWS + wave * 64;

    for (int i = tid; i < K; i += 256) h[i] = 0;   // no barrier needed before use

    // preload A-frags: 4 sets x 4 d-chunks, convert fp32->fp16 inline
    f16x8 a[4][4];
    {
        const float4* x4 = (const float4*)x;
#pragma unroll
        for (int s = 0; s < 4; ++s) {
            int row = rowbase + s * 16 + l15;
#pragma unroll
            for (int c = 0; c < 4; ++c) {
                size_t b4 = ((size_t)row * D + c * 32 + quad * 8) >> 2;
                float4 p = x4[b4], q = x4[b4 + 1];
                f16x8 f;
                f[0] = (_Float16)p.x; f[1] = (_Float16)p.y;
                f[2] = (_Float16)p.z; f[3] = (_Float16)p.w;
                f[4] = (_Float16)q.x; f[5] = (_Float16)q.y;
                f[6] = (_Float16)q.z; f[7] = (_Float16)q.w;
                a[s][c] = f;
            }
        }
    }

    // constant A-frag for the bias row: k-slots 0,1 = 1.0 (quad 0 lanes only)
    U8 acn;
    acn.u.x = (quad == 0) ? 0x3C003C00u : 0u;
    acn.u.y = 0u; acn.u.z = 0u; acn.u.w = 0u;

    float b1[4][4], b2[4][4], idf[4][4];
#pragma unroll
    for (int s = 0; s < 4; ++s)
#pragma unroll
        for (int r = 0; r < 4; ++r) { b1[s][r] = -3.4e38f; b2[s][r] = -3.4e38f; idf[s][r] = 0.f; }

    auto stage = [&](int buf, int cp) {
#pragma unroll
        for (int j = 0; j < 4; ++j) {
            int sec = wave * 4 + j;                  // 0..15, 1 KB sectors
            int row = sec * 4 + (lane >> 4);         // 0..63 (code within group)
            int gblk = (lane & 15) ^ (row & 7);
            const char* g = (const char*)eh + (size_t)cp * 16384 + row * 256 + gblk * 16;
            char* l = (char*)bstage + buf * 16384 + sec * 1024;
            __builtin_amdgcn_global_load_lds((const GLOBAL_AS void*)g,
                                             (LDS_AS void*)l, 16, 0, 0);
        }
    };

    auto load_b = [&](f16x8* dst, unsigned& cnw, int buf, int k, int cb) {
        const unsigned short* bb = bstage + buf * 8192 + k * 2048 + l15 * 128;
#pragma unroll
        for (int c = 0; c < 4; ++c) {
            int blk = (c * 4 + quad) ^ (l15 & 7);
            dst[c] = *(const f16x8*)(bb + blk * 8);
        }
        cnw = cnp[cb + l15];
    };

    auto compute = [&](const f16x8* bfr, unsigned cnw, float colf) {
        U8 bcn;
        bcn.u.x = (quad == 0) ? cnw : 0u;
        bcn.u.y = 0u; bcn.u.z = 0u; bcn.u.w = 0u;
        f32x4 zero = {0.f, 0.f, 0.f, 0.f};
        f32x4 cnacc = __builtin_amdgcn_mfma_f32_16x16x32_f16(acn.v, bcn.v, zero, 0, 0, 0);
#pragma unroll
        for (int s = 0; s < 4; ++s) {
            f32x4 acc = cnacc;
#pragma unroll
            for (int c = 0; c < 4; ++c)
                acc = __builtin_amdgcn_mfma_f32_16x16x32_f16(a[s][c], bfr[c], acc, 0, 0, 0);
#pragma unroll
            for (int r = 0; r < 4; ++r) {
                float sc = acc[r];               // = 2*x.e - ||e||^2 directly
                float old = b1[s][r];
                b1[s][r] = fmaxf(old, sc);
                b2[s][r] = fmaxf(fminf(sc, old), b2[s][r]);
                idf[s][r] = (sc > old) ? colf : idf[s][r];
            }
        }
    };

    constexpr int ITERS = K / 64;   // 16
    stage(0, 0);
    __syncthreads();                // drains vmcnt(0) before barrier

    for (int cp = 0; cp < ITERS; ++cp) {
        if (cp + 1 < ITERS) stage((cp + 1) & 1, cp + 1);
        const int buf = cp & 1;
        const int base = cp * 64;
        f16x8 bf0[4], bf1[4];
        unsigned cw0, cw1;
        load_b(bf0, cw0, buf, 0, base);
        load_b(bf1, cw1, buf, 1, base + 16);
        compute(bf0, cw0, (float)(base + l15));
        compute(bf1, cw1, (float)(base + 16 + l15));
        load_b(bf0, cw0, buf, 2, base + 32);
        load_b(bf1, cw1, buf, 3, base + 48);
        compute(bf0, cw0, (float)(base + 32 + l15));
        compute(bf1, cw1, (float)(base + 48 + l15));
        __syncthreads();            // next-buffer staging landed; this buffer free
    }

    // dump per-lane candidates: row lr has 16 candidates (one per l15)
#pragma unroll
    for (int s = 0; s < 4; ++s)
#pragma unroll
        for (int r = 0; r < 4; ++r) {
            int lr = wave * 64 + s * 16 + quad * 4 + r;
            sb1[lr * 17 + l15] = b1[s][r];
            sb2[lr * 17 + l15] = b2[s][r];
            sid[lr * 17 + l15] = idf[s][r];
        }
    __syncthreads();

    // one thread per row: merge 16 (b1,b2,idx) candidates; histogram locally
    {
        float bs = sb1[tid * 17], ss = sb2[tid * 17], bi = sid[tid * 17];
#pragma unroll
        for (int j = 1; j < 16; ++j) {
            float v = sb1[tid * 17 + j];
            float w = sb2[tid * 17 + j];
            float id = sid[tid * 17 + j];
            if (v > bs) { ss = fmaxf(bs, w); bi = id; bs = v; }
            else {
                ss = fmaxf(ss, v);
                if (v == bs && id < bi) bi = id;
            }
        }
        int grow = blockIdx.x * MROWS + tid;
        out_idx[grow] = bi;
        idx_i32[grow] = (int)bi;
        atomicAdd(&h[(int)bi], 1);
        if (bs - ss < MARGIN) {
            int p = atomicAdd(flag_cnt, 1);
            flag_list[p] = grow;
        }
    }
    __syncthreads();
    for (int i = tid; i < K; i += 256)
        if (h[i]) atomicAdd(&counts_i[i], h[i]);
}

// ---------------------------------------------------------------------------
// Exact fp32 rescore of flagged rows, CODE-SLICED across blocks.
// grid = (chunks grid-stride, RSLICE). Each block: 128 rows x 128 codes.
// Partial per-row argmax merged via packed u64 atomicMax:
//   key = orderable(score) << 32 | (0xFFFF - idx)   (max score, min idx on tie)
// ---------------------------------------------------------------------------
__global__ __launch_bounds__(256, 1) void rescore_part(const float* __restrict__ x,
                                                       const float* __restrict__ embed,
                                                       const float* __restrict__ cnorm,
                                                       const int* __restrict__ flag_cnt,
                                                       const int* __restrict__ flag_list,
                                                       unsigned long long* __restrict__ rkey) {
    __shared__ float xs[128][132];
    __shared__ float es[128][132];

    const int tid = threadIdx.x;
    const int tx = tid & 15;
    const int ty = tid >> 4;
    const int sl = blockIdx.y;                 // code slice: [sl*128, sl*128+128)
    const int cnt = *flag_cnt;
    const int nch = (cnt + 127) >> 7;

    for (int ch = blockIdx.x; ch < nch; ch += gridDim.x) {
        __syncthreads();
        // stage 128 flagged x rows
        {
            const float4* x4 = (const float4*)x;
#pragma unroll
            for (int it = 0; it < 16; ++it) {
                int idx = it * 256 + tid;
                int slot = idx >> 5, c4 = idx & 31;
                int fi = ch * 128 + slot;
                int grow = flag_list[fi < cnt ? fi : cnt - 1];
                float4 v = x4[(size_t)grow * 32 + c4];
                *(float4*)&xs[slot][c4 * 4] = v;
            }
        }
        // stage this slice's 128 embed rows
        {
            const float4* e4 = (const float4*)embed;
            const size_t base4 = (size_t)sl * 128 * 32;
#pragma unroll
            for (int it = 0; it < 16; ++it) {
                int idx = it * 256 + tid;
                int row = idx >> 5, c4 = idx & 31;
                float4 v = e4[base4 + idx];
                *(float4*)&es[row][c4 * 4] = v;
            }
        }
        float cn[8];
#pragma unroll
        for (int c = 0; c < 8; ++c) cn[c] = cnorm[sl * 128 + tx + 16 * c];
        __syncthreads();

        float acc[8][8];
#pragma unroll
        for (int r = 0; r < 8; ++r)
#pragma unroll
            for (int c = 0; c < 8; ++c) acc[r][c] = 0.f;

#pragma unroll 2
        for (int d4 = 0; d4 < 32; ++d4) {
            float4 av[8], bv[8];
#pragma unroll
            for (int r = 0; r < 8; ++r) av[r] = *(const float4*)&xs[ty + 16 * r][4 * d4];
#pragma unroll
            for (int c = 0; c < 8; ++c) bv[c] = *(const float4*)&es[tx + 16 * c][4 * d4];
#pragma unroll
            for (int r = 0; r < 8; ++r)
#pragma unroll
                for (int c = 0; c < 8; ++c) {
                    acc[r][c] = fmaf(av[r].x, bv[c].x, acc[r][c]);
                    acc[r][c] = fmaf(av[r].y, bv[c].y, acc[r][c]);
                    acc[r][c] = fmaf(av[r].z, bv[c].z, acc[r][c]);
                    acc[r][c] = fmaf(av[r].w, bv[c].w, acc[r][c]);
                }
        }

        float best[8];
        int bidx[8];
#pragma unroll
        for (int r = 0; r < 8; ++r) { best[r] = -3.4e38f; bidx[r] = 0; }
#pragma unroll
        for (int r = 0; r < 8; ++r)
#pragma unroll
            for (int c = 0; c < 8; ++c) {
                float s = 2.0f * acc[r][c] - cn[c];
                // codes ascend with c, so strict > keeps the lowest tied index
                if (s > best[r]) { best[r] = s; bidx[r] = sl * 128 + tx + 16 * c; }
            }

        __syncthreads();
        float* sbest = &es[0][0];
        int*   sidx  = (int*)&xs[0][0];
#pragma unroll
        for (int r = 0; r < 8; ++r) {
            int row = ty + 16 * r;
            sbest[row * 16 + tx] = best[r];
            sidx[row * 16 + tx] = bidx[r];
        }
        __syncthreads();
        if (tid < 128) {
            float bs = sbest[tid * 16];
            int bi = sidx[tid * 16];
#pragma unroll
            for (int j = 1; j < 16; ++j) {
                float s = sbest[tid * 16 + j];
                int id = sidx[tid * 16 + j];
                if (s > bs || (s == bs && id < bi)) { bs = s; bi = id; }
            }
            int fi = ch * 128 + tid;
            if (fi < cnt) {
                unsigned ub = __float_as_uint(bs);
                ub = (ub & 0x80000000u) ? ~ub : (ub | 0x80000000u);
                unsigned long long key =
                    ((unsigned long long)ub << 32) | (unsigned)(0xFFFFu - bi);
                atomicMax(&rkey[fi], key);
            }
        }
    }
}

// ---------------------------------------------------------------------------
// scan counts -> offsets/cursor; ncs, total, smoothed (1 block, 1024 thr).
// PROLOGUE (folded rescore_final): unpack rkey for flagged rows, apply
// counts deltas where the exact index differs, finalize idx/out_idx.
// ---------------------------------------------------------------------------
__global__ __launch_bounds__(1024) void scan_cluster_kernel(int* __restrict__ counts_i,
                                                            const float* __restrict__ cluster_size,
                                                            int* __restrict__ offsets,
                                                            int* __restrict__ cursor,
                                                            float* __restrict__ out_ncs,
                                                            float* __restrict__ smoothed,
                                                            const int* __restrict__ flag_cnt,
                                                            const int* __restrict__ flag_list,
                                                            const unsigned long long* __restrict__ rkey,
                                                            int* __restrict__ idx_i32,
                                                            float* __restrict__ out_idx) {
    __shared__ int s[1024];
    __shared__ float red[16];
    __shared__ float total_s;
    int k = threadIdx.x;

    // --- folded rescore_final + counts delta ---
    {
        const int cnt = *flag_cnt;
        for (int i = k; i < cnt; i += 1024) {
            unsigned long long key = rkey[i];
            int bi = 0xFFFF - (int)(key & 0xFFFFFFFFull);
            int grow = flag_list[i];
            int old = idx_i32[grow];
            if (old != bi) {
                atomicAdd(&counts_i[old], -1);
                atomicAdd(&counts_i[bi], 1);
                idx_i32[grow] = bi;
                out_idx[grow] = (float)bi;
            }
        }
    }
    __syncthreads();

    int c = atomicAdd(&counts_i[k], 0);   // L1-bypassing read (atomic visibility)
    s[k] = c;
    __syncthreads();
    for (int off = 1; off < 1024; off <<= 1) {
        int v = (k >= off) ? s[k - off] : 0;
        __syncthreads();
        s[k] += v;
        __syncthreads();
    }
    int offx = s[k] - c;   // exclusive
    offsets[k] = offx;
    cursor[k] = offx;

    float ncs = cluster_size[k] * DECAYF + OMDF * (float)c;
    out_ncs[k] = ncs;

    float v = ncs;
#pragma unroll
    for (int off = 32; off >= 1; off >>= 1) v += __shfl_down(v, off, 64);
    if ((k & 63) == 0) red[k >> 6] = v;
    __syncthreads();
    if (k < 16) {
        float t = red[k];
#pragma unroll
        for (int off = 8; off >= 1; off >>= 1) t += __shfl_down(t, off, 16);
        if (k == 0) total_s = t;
    }
    __syncthreads();
    float total = total_s;
    smoothed[k] = (ncs + EPSF) / (total + (float)K * EPSF) * total;
}

// ---------------------------------------------------------------------------
// scatter row ids (and their code) into per-code segments
// ---------------------------------------------------------------------------
__global__ __launch_bounds__(256) void scatter_kernel(const int* __restrict__ idx_i32,
                                                      int* __restrict__ cursor,
                                                      int* __restrict__ rowlist,
                                                      int* __restrict__ codelist) {
    int row = blockIdx.x * 256 + threadIdx.x;
    int code = idx_i32[row];
    int pos = atomicAdd(&cursor[code], 1);
    rowlist[pos] = row;
    codelist[pos] = code;
}

// ---------------------------------------------------------------------------
// Flat segmented gather-sum: each block owns exactly CHUNK consecutive
// rowlist entries (perfect balance). Register run-accumulation; atomic
// flush only at run boundaries.
// ---------------------------------------------------------------------------
__global__ __launch_bounds__(128) void segsum_flat(const float* __restrict__ x,
                                                   const int* __restrict__ rowlist,
                                                   const int* __restrict__ codelist,
                                                   float* __restrict__ embed_sum) {
    const int d = threadIdx.x;
    const int lo = blockIdx.x * CHUNK;

    float acc = 0.f;
    int cur = codelist[lo];
    for (int i = lo; i < lo + CHUNK; i += 8) {
        int r[8], c[8];
        float v[8];
#pragma unroll
        for (int j = 0; j < 8; ++j) {
            r[j] = rowlist[i + j];
            c[j] = codelist[i + j];
        }
#pragma unroll
        for (int j = 0; j < 8; ++j) v[j] = x[(size_t)r[j] * D + d];
#pragma unroll
        for (int j = 0; j < 8; ++j) {
            if (c[j] != cur) {
                atomicAdd(&embed_sum[(size_t)cur * D + d], acc);
                acc = 0.f;
                cur = c[j];
            }
            acc += v[j];
        }
    }
    atomicAdd(&embed_sum[(size_t)cur * D + d], acc);
}

// ---------------------------------------------------------------------------
// Fused finalize: blocks [0,128) do new_embed_avg / new_embed; blocks
// [128, 128+16384) do quantized[row] = embed[idx[row]]. The two halves are
// mutually independent; fusing saves a graph node.
// ---------------------------------------------------------------------------
constexpr int UPD_BLOCKS = (K * D / 4) / 256;          // 128
constexpr int GATH_BLOCKS = (N_ROWS * 32) / 256;       // 16384

__global__ __launch_bounds__(256) void finalize_kernel(const float* __restrict__ embed_avg,
                                                       const float* __restrict__ embed_sum,
                                                       const float* __restrict__ smoothed,
                                                       float* __restrict__ out_nea,
                                                       float* __restrict__ out_ne,
                                                       const float* __restrict__ embed,
                                                       const int* __restrict__ idx_i32,
                                                       float* __restrict__ quant) {
    const int b = blockIdx.x;
    if (b < UPD_BLOCKS) {
        int t = b * 256 + threadIdx.x;
        float4 ea = ((const float4*)embed_avg)[t];
        float4 es = ((const float4*)embed_sum)[t];
        float sm = smoothed[t >> 5];
        float4 nea;
        nea.x = ea.x * DECAYF + OMDF * es.x;
        nea.y = ea.y * DECAYF + OMDF * es.y;
        nea.z = ea.z * DECAYF + OMDF * es.z;
        nea.w = ea.w * DECAYF + OMDF * es.w;
        ((float4*)out_nea)[t] = nea;
        float4 ne;
        ne.x = nea.x / sm; ne.y = nea.y / sm; ne.z = nea.z / sm; ne.w = nea.w / sm;
        ((float4*)out_ne)[t] = ne;
    } else {
        int t = (b - UPD_BLOCKS) * 256 + threadIdx.x;
        int row = t >> 5;
        int j = t & 31;
        int k = idx_i32[row];
        ((float4*)quant)[(size_t)row * 32 + j] = ((const float4*)embed)[(size_t)k * 32 + j];
    }
}

// ---------------------------------------------------------------------------
extern "C" void kernel_launch(void* const* d_in, const int* in_sizes, int n_in,
                              void* d_out, int out_size, void* d_ws, size_t ws_size,
                              hipStream_t stream) {
    const float* x            = (const float*)d_in[0];
    const float* embed        = (const float*)d_in[1];
    const float* embed_avg    = (const float*)d_in[2];
    const float* cluster_size = (const float*)d_in[3];

    float* out       = (float*)d_out;
    float* out_quant = out;
    float* out_idx   = out_quant + (size_t)N_ROWS * D;
    float* out_ne    = out_idx + N_ROWS;
    float* out_ncs   = out_ne + (size_t)K * D;
    float* out_nea   = out_ncs + K;

    // scratch in the quantized output region (overwritten by finalize last):
    //   rkey: u64 argmax keys for flagged rows (1 MB)
    //   codelist: per-rowlist-slot code ids (0.5 MB)
    unsigned long long* rkey = (unsigned long long*)out_quant;
    int* codelist = (int*)(rkey + N_ROWS);

    // workspace (~2.4 MB)
    int*   counts_i  = (int*)d_ws;                        // K (+4 pad incl flag_cnt)
    int*   flag_cnt  = counts_i + K;                      // 1 (+3 pad)
    int*   idx_i32   = counts_i + K + 4;                  // N
    int*   flag_list = idx_i32 + N_ROWS;                  // N
    int*   offsets   = flag_list + N_ROWS;                // K
    int*   cursor    = offsets + K;                       // K
    int*   rowlist   = cursor + K;                        // N
    float* cnorm     = (float*)(rowlist + N_ROWS);        // K
    float* smoothed  = cnorm + K;                         // K
    unsigned* cnp    = (unsigned*)(smoothed + K);         // K
    float* embed_sum = (float*)(cnp + K);                 // K*D
    unsigned short* eh = (unsigned short*)(embed_sum + (size_t)K * D);  // K*D f16

    // 7 graph nodes (was 10): prep(+3 memsets), dist(+hist), rescore,
    // scan(+rescore_final), scatter, segsum, finalize(update+gather)
    prep_embed<<<64, 256, 0, stream>>>(embed, eh, cnorm, cnp, counts_i, embed_sum, rkey);
    mfma_dist<<<N_ROWS / MROWS, 256, 0, stream>>>(x, eh, cnp, out_idx, idx_i32,
                                                  flag_cnt, flag_list, counts_i);
    rescore_part<<<dim3(128, RSLICE), 256, 0, stream>>>(x, embed, cnorm, flag_cnt,
                                                        flag_list, rkey);
    scan_cluster_kernel<<<1, 1024, 0, stream>>>(counts_i, cluster_size, offsets, cursor,
                                                out_ncs, smoothed, flag_cnt, flag_list,
                                                rkey, idx_i32, out_idx);
    scatter_kernel<<<N_ROWS / 256, 256, 0, stream>>>(idx_i32, cursor, rowlist, codelist);
    segsum_flat<<<N_ROWS / CHUNK, 128, 0, stream>>>(x, rowlist, codelist, embed_sum);
    finalize_kernel<<<UPD_BLOCKS + GATH_BLOCKS, 256, 0, stream>>>(embed_avg, embed_sum,
                                                                  smoothed, out_nea, out_ne,
                                                                  embed, idx_i32, out_quant);
}